// Round 9
// baseline (93.589 us; speedup 1.0000x reference)
//
#include <hip/hip_runtime.h>

constexpr int N    = 128;
constexpr int C    = 2048;
constexpr int KP   = 4;
constexpr int KN   = 508;
constexpr int K    = 512;      // KP + KN
constexpr int NK   = N * K;    // 65536 gathers
constexpr int NC   = 50000;    // memory bank rows
constexpr int MAXD = 32;       // pair slots per idx; P(cnt>32) ~ 1e-24 -> no overflow path
constexpr int GRP  = 4;        // pairs served per work item (one row stream)

// ws layout (ints):
//   hdr:  count[NC] | wcount                  <- one hipMemsetAsync(0)
//   rest: pairs[NC*MAXD] | work[NK+64] | row_loss(f32)[N]
constexpr int HDR_INTS = NC + 1;

__device__ __forceinline__ int gather_idx(const int* pos_idx, const int* neg_idx, int n, int k) {
    return (k < KP) ? pos_idx[n * KP + k] : neg_idx[n * KN + (k - KP)];
}

// Append each (n,k) to its idx's slot list. The claimer of each group-of-4
// slot also appends a work item (idx<<3 | group) -> main kernel waves all
// do useful work and every pair belongs to exactly one work item.
__global__ __launch_bounds__(256) void build_kernel(
    const int* __restrict__ pos_idx, const int* __restrict__ neg_idx,
    int* __restrict__ count, int* __restrict__ wcount,
    int* __restrict__ pairs, int* __restrict__ work)
{
    const int t = blockIdx.x * 256 + threadIdx.x;   // < NK
    const int n = t >> 9, k = t & (K - 1);
    const int idx = gather_idx(pos_idx, neg_idx, n, k);
    const int p = atomicAdd(&count[idx], 1);
    if (p < MAXD) {
        pairs[idx * MAXD + p] = (n << 9) | k;
        if ((p & (GRP - 1)) == 0) {
            const int w = atomicAdd(wcount, 1);
            work[w] = (idx << 3) | (p >> 2);   // group id 0..7 (MAXD/GRP = 8)
        }
    }
}

// Serve MM pairs while streaming the M row once: per iteration 1 HBM chunk +
// MM L2-hot inputs chunks, consumed immediately -> round-2-shaped loop,
// tiny register footprint, full occupancy.
template<int MM>
__device__ __forceinline__ void serve_group(
    const float4* __restrict__ b,      // M row base (+lane)
    const float4* __restrict__ A,      // inputs base (+lane)
    const int*    pk,                  // MM packed (n<<9|k)
    float*        __restrict__ logits,
    int lane)
{
    const float4* a[MM];
    float acc[MM];
    #pragma unroll
    for (int j = 0; j < MM; ++j) {
        a[j]   = A + (size_t)(pk[j] >> 9) * (C / 4);
        acc[j] = 0.f;
    }
    #pragma unroll 4
    for (int i = 0; i < 8; ++i) {      // 8 x 16 B/lane = full 8 KB row
        const float4 mv = b[i * 64];
        #pragma unroll
        for (int j = 0; j < MM; ++j) {
            const float4 av = a[j][i * 64];
            acc[j] = fmaf(mv.x, av.x, acc[j]);
            acc[j] = fmaf(mv.y, av.y, acc[j]);
            acc[j] = fmaf(mv.z, av.z, acc[j]);
            acc[j] = fmaf(mv.w, av.w, acc[j]);
        }
    }
    #pragma unroll
    for (int j = 0; j < MM; ++j) {
        float v = acc[j];
        #pragma unroll
        for (int off = 32; off > 0; off >>= 1)
            v += __shfl_down(v, off, 64);
        if (lane == 0)
            logits[(pk[j] >> 9) * K + (pk[j] & (K - 1))] = v;
    }
}

__global__ __launch_bounds__(256, 8) void gemv_dedup_kernel(
    const float* __restrict__ inputs,
    const float* __restrict__ M,
    const int*   __restrict__ count,
    const int*   __restrict__ pairs,
    const int*   __restrict__ work,
    const int*   __restrict__ wcount,
    float*       __restrict__ logits)
{
    const int wave = threadIdx.x >> 6;
    const int lane = threadIdx.x & 63;
    const int g    = blockIdx.x * 4 + wave;
    if (g >= *wcount) return;

    const int item = work[g];
    const int idx  = item >> 3;
    const int grp  = item & 7;
    const int cnt  = count[idx];
    int m = cnt - (grp << 2);
    m = m > GRP ? GRP : m;             // 1..4, wave-uniform

    const int4 pp = *reinterpret_cast<const int4*>(&pairs[idx * MAXD + (grp << 2)]);
    const int  pk[4] = {pp.x, pp.y, pp.z, pp.w};

    const float4* b = reinterpret_cast<const float4*>(M + (size_t)idx * C) + lane;
    const float4* A = reinterpret_cast<const float4*>(inputs) + lane;

    switch (m) {                        // wave-uniform -> scalar branch
        case 1: serve_group<1>(b, A, pk, logits, lane); break;
        case 2: serve_group<2>(b, A, pk, logits, lane); break;
        case 3: serve_group<3>(b, A, pk, logits, lane); break;
        default: serve_group<4>(b, A, pk, logits, lane); break;
    }
}

__global__ __launch_bounds__(512) void softmax_loss_kernel(
    const float* __restrict__ logits,
    const float* __restrict__ cof,
    float*       __restrict__ row_loss)
{
    __shared__ float red[8];
    __shared__ float xs[KP];
    const int n    = blockIdx.x;
    const int t    = threadIdx.x;
    const int wid  = t >> 6;
    const int lane = t & 63;

    float x = logits[n * K + t];

    float m = x;
    #pragma unroll
    for (int off = 1; off < 64; off <<= 1)
        m = fmaxf(m, __shfl_xor(m, off, 64));
    if (lane == 0) red[wid] = m;
    __syncthreads();
    float bm = red[0];
    #pragma unroll
    for (int i = 1; i < 8; ++i) bm = fmaxf(bm, red[i]);

    float s = expf(x - bm);
    #pragma unroll
    for (int off = 1; off < 64; off <<= 1)
        s += __shfl_xor(s, off, 64);
    __syncthreads();
    if (lane == 0) red[wid] = s;
    if (t < KP) xs[t] = x;
    __syncthreads();

    if (t == 0) {
        float bs = 0.f;
        #pragma unroll
        for (int i = 0; i < 8; ++i) bs += red[i];
        const float logZ = bm + logf(bs);
        float acc = 0.f;
        #pragma unroll
        for (int j = 0; j < KP; ++j)
            acc += cof[j] * (xs[j] - logZ);
        row_loss[n] = acc;
    }
}

__global__ __launch_bounds__(128) void loss_reduce_kernel(
    const float* __restrict__ row_loss,
    float*       __restrict__ out)
{
    const int t = threadIdx.x;
    float v = row_loss[t];
    #pragma unroll
    for (int off = 1; off < 64; off <<= 1)
        v += __shfl_xor(v, off, 64);
    __shared__ float red[2];
    if ((t & 63) == 0) red[t >> 6] = v;
    __syncthreads();
    if (t == 0) out[0] = -(red[0] + red[1]) / (float)N;
}

// Fallback (round-2 structure) if ws is too small.
__global__ __launch_bounds__(256) void logits_kernel(
    const float* __restrict__ inputs,
    const int*   __restrict__ pos_idx,
    const int*   __restrict__ neg_idx,
    const float* __restrict__ M,
    float*       __restrict__ logits)
{
    const int wave = threadIdx.x >> 6;
    const int lane = threadIdx.x & 63;
    const int n    = blockIdx.y;
    const int k    = (blockIdx.x << 2) + wave;

    const int idx = (k < KP) ? pos_idx[n * KP + k]
                             : neg_idx[n * KN + (k - KP)];

    const float4* __restrict__ a = reinterpret_cast<const float4*>(inputs + (size_t)n * C);
    const float4* __restrict__ b = reinterpret_cast<const float4*>(M + (size_t)idx * C);

    float acc = 0.f;
    #pragma unroll
    for (int i = 0; i < C / (4 * 64); ++i) {
        float4 av = a[i * 64 + lane];
        float4 bv = b[i * 64 + lane];
        acc = fmaf(av.x, bv.x, acc);
        acc = fmaf(av.y, bv.y, acc);
        acc = fmaf(av.z, bv.z, acc);
        acc = fmaf(av.w, bv.w, acc);
    }
    #pragma unroll
    for (int off = 32; off > 0; off >>= 1)
        acc += __shfl_down(acc, off, 64);
    if (lane == 0) logits[n * K + k] = acc;
}

extern "C" void kernel_launch(void* const* d_in, const int* in_sizes, int n_in,
                              void* d_out, int out_size, void* d_ws, size_t ws_size,
                              hipStream_t stream) {
    const float* inputs  = (const float*)d_in[0];
    const int*   pos_idx = (const int*)d_in[1];
    const int*   neg_idx = (const int*)d_in[2];
    const float* cof     = (const float*)d_in[3];
    const float* M       = (const float*)d_in[4];

    float* out    = (float*)d_out;
    float* logits = out + 1;            // d_out = [loss(1), logits(128*512)]

    const size_t need = (size_t)(HDR_INTS + (size_t)NC * MAXD + (NK + 64) + N) * 4;
    if (ws_size >= need) {
        int*   count    = (int*)d_ws;
        int*   wcount   = count + NC;
        int*   pairs    = count + HDR_INTS;
        int*   work     = pairs + (size_t)NC * MAXD;
        float* row_loss = (float*)(work + NK + 64);

        hipMemsetAsync(count, 0, (size_t)HDR_INTS * 4, stream);
        build_kernel<<<NK / 256, 256, 0, stream>>>(pos_idx, neg_idx, count, wcount, pairs, work);
        // grid covers worst-case work items (<= NK); surplus waves exit on wcount
        gemv_dedup_kernel<<<NK / 4 + 16, 256, 0, stream>>>(inputs, M, count, pairs, work, wcount, logits);
        softmax_loss_kernel<<<N, K, 0, stream>>>(logits, cof, row_loss);
        loss_reduce_kernel<<<1, N, 0, stream>>>(row_loss, out);
    } else {
        float* row_loss = (float*)d_ws;
        logits_kernel<<<dim3(K / 4, N), 256, 0, stream>>>(inputs, pos_idx, neg_idx, M, logits);
        softmax_loss_kernel<<<N, K, 0, stream>>>(logits, cof, row_loss);
        loss_reduce_kernel<<<1, N, 0, stream>>>(row_loss, out);
    }
}